// Round 3
// baseline (620.637 us; speedup 1.0000x reference)
//
#include <hip/hip_runtime.h>

// Problem constants (match reference file)
#define N_NODES 2000000
#define N_EDGES 32000000
#define N_OUT   400000   // N_NODES / 5
#define EPT     16       // edges per thread

typedef int  iv4 __attribute__((ext_vector_type(4)));   // native vector for nontemporal builtin

// Edge scatter: for each edge (src, dst), if dst % 5 == 0 accumulate x[src]
// into agg[dst/5]. Only those nodes survive the final reshape(-1,5)[:,0].
//
// Latency-hiding structure (R1 was latency-bound: 24% HBM, VALU 3%):
//  - 16 edges/thread; src+dst rows loaded unconditionally as 8 x 16B
//    nontemporal loads issued back-to-back (~128 lines in flight/wave).
//  - nontemporal keeps the 256 MB index stream from evicting the 8 MB x
//    array out of per-XCD L2 (gather hit rate).
//  - all masked x-gathers issued as a group, then all atomics (fire-and-
//    forget device-scope adds; no dependent wait).
__global__ __launch_bounds__(256) void gcn_edge_scatter(
    const int* __restrict__ src,
    const int* __restrict__ dst,
    const float* __restrict__ x,
    float* __restrict__ agg)
{
    const long long base = ((long long)blockIdx.x * blockDim.x + threadIdx.x) * EPT;
    if (base >= N_EDGES) return;  // N_EDGES % EPT == 0, so a live thread has a full batch

    iv4 d4[EPT / 4], s4[EPT / 4];
#pragma unroll
    for (int c = 0; c < EPT / 4; ++c)
        d4[c] = __builtin_nontemporal_load(reinterpret_cast<const iv4*>(dst + base) + c);
#pragma unroll
    for (int c = 0; c < EPT / 4; ++c)
        s4[c] = __builtin_nontemporal_load(reinterpret_cast<const iv4*>(src + base) + c);

    int dd[EPT], ss[EPT];
#pragma unroll
    for (int c = 0; c < EPT / 4; ++c) {
#pragma unroll
        for (int j = 0; j < 4; ++j) {
            dd[c * 4 + j] = d4[c][j];
            ss[c * 4 + j] = s4[c][j];
        }
    }

    // Phase 1: issue all masked gathers (independent, pipeline in vmcnt queue)
    float v[EPT];
#pragma unroll
    for (int k = 0; k < EPT; ++k) {
        v[k] = 0.0f;
        if (dd[k] % 5 == 0) v[k] = x[ss[k]];
    }
    // Phase 2: fire-and-forget atomics
#pragma unroll
    for (int k = 0; k < EPT; ++k) {
        if (dd[k] % 5 == 0) atomicAdd(&agg[dd[k] / 5], v[k]);
    }
}

// Epilogue: agg_node = agg_raw * w_conv + b_conv, then the 2->4->1 MLP with
// both input columns identical: t_j = relu(agg*(w1[0,j]+w1[1,j]) + b1[j]),
// out = sum_j t_j * w2[j] + b2.
__global__ __launch_bounds__(256) void gcn_epilogue(
    const float* __restrict__ agg,
    const float* __restrict__ w_conv,
    const float* __restrict__ b_conv,
    const float* __restrict__ w1,   // [2,4] row-major
    const float* __restrict__ b1,   // [4]
    const float* __restrict__ w2,   // [4,1]
    const float* __restrict__ b2,   // [1]
    float* __restrict__ out)
{
    const int i = blockIdx.x * blockDim.x + threadIdx.x;
    if (i >= N_OUT) return;
    const float wc = w_conv[0];
    const float bc = b_conv[0];
    const float a = agg[i] * wc + bc;
    float r = b2[0];
#pragma unroll
    for (int j = 0; j < 4; ++j) {
        float t = fmaf(a, w1[j] + w1[4 + j], b1[j]);
        t = fmaxf(t, 0.0f);
        r = fmaf(t, w2[j], r);
    }
    out[i] = r;
}

extern "C" void kernel_launch(void* const* d_in, const int* in_sizes, int n_in,
                              void* d_out, int out_size, void* d_ws, size_t ws_size,
                              hipStream_t stream) {
    const float* x      = (const float*)d_in[0];
    const int*   ei     = (const int*)  d_in[1];  // [2, N_EDGES]: src row then dst row
    const float* w_conv = (const float*)d_in[2];
    const float* b_conv = (const float*)d_in[3];
    const float* w1     = (const float*)d_in[4];
    const float* b1     = (const float*)d_in[5];
    const float* w2     = (const float*)d_in[6];
    const float* b2     = (const float*)d_in[7];
    float* out = (float*)d_out;
    float* agg = (float*)d_ws;   // N_OUT floats of scratch (harness poisons -> zero it)

    (void)hipMemsetAsync(agg, 0, (size_t)N_OUT * sizeof(float), stream);

    // 32M edges / 16 per thread = 2M threads -> 7813 blocks of 256 (last partial).
    gcn_edge_scatter<<<(N_EDGES / EPT + 255) / 256, 256, 0, stream>>>(
        ei, ei + N_EDGES, x, agg);

    gcn_epilogue<<<(N_OUT + 255) / 256, 256, 0, stream>>>(
        agg, w_conv, b_conv, w1, b1, w2, b2, out);
}

// Round 4
// 620.410 us; speedup vs baseline: 1.0004x; 1.0004x over previous
//
#include <hip/hip_runtime.h>

// Problem constants (match reference file)
#define N_NODES 2000000
#define N_EDGES 32000000
#define N_OUT   400000   // N_NODES / 5
#define EPT     16       // edges per thread

typedef int  iv4 __attribute__((ext_vector_type(4)));   // native vector for nontemporal builtin

// Edge scatter: for each edge (src, dst), if dst % 5 == 0 accumulate x[src]
// into agg[dst/5]. Only those nodes survive the final reshape(-1,5)[:,0].
//
// R3 post-mortem: compiler allocated only 24 VGPRs -> ~1 outstanding request
// per wave -> latency-bound at 1.9 TB/s. Fixes here:
//  - __launch_bounds__(256, 4): VGPR cap 128, occupancy objective relaxed.
//  - gathers are UNCONDITIONAL with sanitized index (masked lanes read x[0],
//    one broadcast line) so they compile to 16 back-to-back global_load_dword
//    with a single waitcnt, instead of exec-masked serialized loads.
//  - atomics remain conditional + fire-and-forget at the end.
__global__ __launch_bounds__(256, 4) void gcn_edge_scatter(
    const int* __restrict__ src,
    const int* __restrict__ dst,
    const float* __restrict__ x,
    float* __restrict__ agg)
{
    const long long base = ((long long)blockIdx.x * blockDim.x + threadIdx.x) * EPT;
    if (base >= N_EDGES) return;  // N_EDGES % EPT == 0: live thread => full batch

    iv4 d4[EPT / 4], s4[EPT / 4];
#pragma unroll
    for (int c = 0; c < EPT / 4; ++c)
        d4[c] = __builtin_nontemporal_load(reinterpret_cast<const iv4*>(dst + base) + c);
#pragma unroll
    for (int c = 0; c < EPT / 4; ++c)
        s4[c] = __builtin_nontemporal_load(reinterpret_cast<const iv4*>(src + base) + c);

    int dd[EPT];
    int idx[EPT];
    bool pass[EPT];
#pragma unroll
    for (int c = 0; c < EPT / 4; ++c) {
#pragma unroll
        for (int j = 0; j < 4; ++j) {
            const int d = d4[c][j];
            const int s = s4[c][j];
            const bool p = (d % 5 == 0);
            dd[c * 4 + j]   = d;
            pass[c * 4 + j] = p;
            idx[c * 4 + j]  = p ? s : 0;   // masked lanes -> x[0] (broadcast line)
        }
    }

    // Unconditional gathers: 16 independent loads, one wait.
    float v[EPT];
#pragma unroll
    for (int k = 0; k < EPT; ++k)
        v[k] = x[idx[k]];

    // Fire-and-forget atomics (conditional, no dependent read).
#pragma unroll
    for (int k = 0; k < EPT; ++k)
        if (pass[k]) atomicAdd(&agg[dd[k] / 5], v[k]);
}

// Epilogue: agg_node = agg_raw * w_conv + b_conv, then the 2->4->1 MLP with
// both input columns identical: t_j = relu(agg*(w1[0,j]+w1[1,j]) + b1[j]),
// out = sum_j t_j * w2[j] + b2.
__global__ __launch_bounds__(256) void gcn_epilogue(
    const float* __restrict__ agg,
    const float* __restrict__ w_conv,
    const float* __restrict__ b_conv,
    const float* __restrict__ w1,   // [2,4] row-major
    const float* __restrict__ b1,   // [4]
    const float* __restrict__ w2,   // [4,1]
    const float* __restrict__ b2,   // [1]
    float* __restrict__ out)
{
    const int i = blockIdx.x * blockDim.x + threadIdx.x;
    if (i >= N_OUT) return;
    const float wc = w_conv[0];
    const float bc = b_conv[0];
    const float a = agg[i] * wc + bc;
    float r = b2[0];
#pragma unroll
    for (int j = 0; j < 4; ++j) {
        float t = fmaf(a, w1[j] + w1[4 + j], b1[j]);
        t = fmaxf(t, 0.0f);
        r = fmaf(t, w2[j], r);
    }
    out[i] = r;
}

extern "C" void kernel_launch(void* const* d_in, const int* in_sizes, int n_in,
                              void* d_out, int out_size, void* d_ws, size_t ws_size,
                              hipStream_t stream) {
    const float* x      = (const float*)d_in[0];
    const int*   ei     = (const int*)  d_in[1];  // [2, N_EDGES]: src row then dst row
    const float* w_conv = (const float*)d_in[2];
    const float* b_conv = (const float*)d_in[3];
    const float* w1     = (const float*)d_in[4];
    const float* b1     = (const float*)d_in[5];
    const float* w2     = (const float*)d_in[6];
    const float* b2     = (const float*)d_in[7];
    float* out = (float*)d_out;
    float* agg = (float*)d_ws;   // N_OUT floats of scratch (harness poisons -> zero it)

    (void)hipMemsetAsync(agg, 0, (size_t)N_OUT * sizeof(float), stream);

    // 32M edges / 16 per thread = 2M threads -> 7813 blocks of 256 (last partial).
    gcn_edge_scatter<<<(N_EDGES / EPT + 255) / 256, 256, 0, stream>>>(
        ei, ei + N_EDGES, x, agg);

    gcn_epilogue<<<(N_OUT + 255) / 256, 256, 0, stream>>>(
        agg, w_conv, b_conv, w1, b1, w2, b2, out);
}